// Round 7
// baseline (128.481 us; speedup 1.0000x reference)
//
#include <hip/hip_runtime.h>
#include <hip/hip_bf16.h>
#include <math.h>

// Problem constants (fixed by the reference).
#define B_  16
#define N_  16384
#define D_  64
#define K_  64
#define OUT_PER_B (K_ + 2*K_*D_)   // 8256
#define CHUNKS 64
#define NTILES (N_ / CHUNKS / 64)  // 4

// ws layout:
//   float[0,4096)    Wt bf16 [64 k][128 kd] as 8192 ushorts: kd<64 = -0.5/var, kd>=64 = mu/var
//   float[4096,4160) c0[k] = log(pi[k]) - 0.5*(D*log(2pi) + sum log var + sum mu^2/var)
//   byte region at WS_PART_OFF floats: per (b,chunk) partial record:
//     f32 qsum[64] | bf16 qx[64*64] | bf16 qx2[64*64]   (16640 B, stride PART_STRIDE)
#define WS_C0_OFF   4096
#define WS_PART_OFF 4160
#define PART_STRIDE (64*4 + 2*4096*2)   // 16640 bytes

typedef float f32x4 __attribute__((ext_vector_type(4)));
typedef short short8 __attribute__((ext_vector_type(8)));

union U8 { short8 s8; unsigned int u[4]; };

__device__ __forceinline__ unsigned short f2bf(float f) {
    union { float f; unsigned int u; } v; v.f = f;
    unsigned int r = v.u + 0x7FFFu + ((v.u >> 16) & 1u);   // round-to-nearest-even
    return (unsigned short)(r >> 16);
}

// packed RNE f32x2 -> bf16x2 (v_cvt_pk_bf16_f32 on gfx950)
__device__ __forceinline__ unsigned int f2bf2(float lo, float hi) {
    __hip_bfloat162 h = __float22bfloat162_rn(make_float2(lo, hi));
    unsigned int u;
    __builtin_memcpy(&u, &h, 4);
    return u;
}

__device__ __forceinline__ float bf2f(unsigned short u) {
    unsigned int v = ((unsigned int)u) << 16;
    float f;
    __builtin_memcpy(&f, &v, 4);
    return f;
}

__global__ __launch_bounds__(256) void fv_prep(const float* __restrict__ pi,
                                               const float* __restrict__ mu,
                                               const float* __restrict__ var,
                                               float* __restrict__ ws) {
    __shared__ float red[256];
    int t = threadIdx.x;
    unsigned short* wt = (unsigned short*)ws;
    for (int i = t; i < 4096; i += 256) {        // i = k*64 + d
        int k = i >> 6, d = i & 63;
        float v  = var[i];
        float m  = mu[i];
        float iv = 1.0f / v;
        wt[k * 128 + d]      = f2bf(-0.5f * iv);
        wt[k * 128 + 64 + d] = f2bf(m * iv);
    }
    // c0: 4 threads per k, 16 dims each
    int k = t >> 2, pr = t & 3;
    float s = 0.0f;
    #pragma unroll
    for (int j = 0; j < 16; ++j) {
        int d = pr * 16 + j;
        float v = var[k * 64 + d];
        float m = mu[k * 64 + d];
        s += __logf(v) + m * m / v;
    }
    red[t] = s;
    __syncthreads();
    if (pr == 0) {
        float sum = red[4 * k] + red[4 * k + 1] + red[4 * k + 2] + red[4 * k + 3];
        // D*log(2*pi) = 117.6241322501981
        ws[WS_C0_OFF + k] = __logf(pi[k]) - 0.5f * (117.6241322502f + sum);
    }
}

// MFMA layouts (16x16x32 bf16, guide-verified):
//   A[m = lane&15][kk = (lane>>4)*8 + j]
//   B[kk = (lane>>4)*8 + j][n = lane&15]
//   C/D: col = lane&15, row = 4*(lane>>4) + reg
__global__ __launch_bounds__(256, 3) void fv_main(const float* __restrict__ x,
                                                  const float* __restrict__ ws,
                                                  char* __restrict__ partials) {
    // Wt shared in LDS (R7: was 64 VGPR/lane duplicated across all 4 waves)
    __shared__ __align__(16) unsigned short WtS[64 * 136];    // stride 136: bank phase 2-way = free
    __shared__ float c0s[64];
    __shared__ __align__(16) unsigned short QtS[2][64 * 72];  // double-buffered Q^T[k][p]
    __shared__ float qsum_s[4][64];

    const int t    = threadIdx.x;
    const int w    = t >> 6;        // wave 0..3
    const int lane = t & 63;
    const int r16  = lane & 15;
    const int q    = lane >> 4;     // quad 0..3

    // ---- stage Wt + c0 into LDS (once; 16 x 16B chunks per 128-ushort row) ----
    {
        const uint4* src = (const uint4*)ws;            // 1024 x 16B chunks
        for (int i = t; i < 1024; i += 256) {
            int row = i >> 4, u = i & 15;
            *(uint4*)&WtS[row * 136 + u * 8] = src[i];
        }
        if (t < 64) c0s[t] = ws[WS_C0_OFF + t];
    }

    const int bi    = blockIdx.y;
    const int chunk = blockIdx.x;
    const int ppb   = N_ / CHUNKS;
    const float* xb = x + ((size_t)bi * N_ + (size_t)chunk * ppb) * D_;

    f32x4 accX[4]  = {};       // Qx  : k rows, d col = 16w + r16
    f32x4 accX2[4] = {};       // Qx2
    float qsacc[4][4] = {};    // per-lane Q sums (ks: 16kt + 4q + rr)

    const int rowoff = (16 * w + r16) * D_ + 8 * q;   // phase-1 row base
    const int dcol   = 16 * w + r16;                  // phase-2 column

    // ---- preload tile-0 phase-1 rows ----
    float4 va, vb, vc, vd;
    {
        const float* xr = xb + rowoff;
        va = *(const float4*)(xr);
        vb = *(const float4*)(xr + 4);
        vc = *(const float4*)(xr + 32);
        vd = *(const float4*)(xr + 36);
    }

    __syncthreads();           // WtS/c0s ready

    #pragma unroll 2
    for (int tile = 0; tile < NTILES; ++tile) {
        const float* xt = xb + (size_t)tile * 64 * D_;

        // ---- prefetch next tile's rows (stays in flight across the manual barrier) ----
        float4 nva, nvb, nvc, nvd;
        if (tile + 1 < NTILES) {
            const float* xr = xt + 64 * D_ + rowoff;
            nva = *(const float4*)(xr);
            nvb = *(const float4*)(xr + 4);
            nvc = *(const float4*)(xr + 32);
            nvd = *(const float4*)(xr + 36);
        }

        // ================= phase 1: S^T[k][p] =================
        U8 fxa, fxb, fx2a, fx2b;
        fxa.u[0]  = f2bf2(va.x, va.y);           fxa.u[1]  = f2bf2(va.z, va.w);
        fxa.u[2]  = f2bf2(vb.x, vb.y);           fxa.u[3]  = f2bf2(vb.z, vb.w);
        fxb.u[0]  = f2bf2(vc.x, vc.y);           fxb.u[1]  = f2bf2(vc.z, vc.w);
        fxb.u[2]  = f2bf2(vd.x, vd.y);           fxb.u[3]  = f2bf2(vd.z, vd.w);
        fx2a.u[0] = f2bf2(va.x*va.x, va.y*va.y); fx2a.u[1] = f2bf2(va.z*va.z, va.w*va.w);
        fx2a.u[2] = f2bf2(vb.x*vb.x, vb.y*vb.y); fx2a.u[3] = f2bf2(vb.z*vb.z, vb.w*vb.w);
        fx2b.u[0] = f2bf2(vc.x*vc.x, vc.y*vc.y); fx2b.u[1] = f2bf2(vc.z*vc.z, vc.w*vc.w);
        fx2b.u[2] = f2bf2(vd.x*vd.x, vd.y*vd.y); fx2b.u[3] = f2bf2(vd.z*vd.z, vd.w*vd.w);

        float sc[4][4];
        #pragma unroll
        for (int kt = 0; kt < 4; ++kt) {
            const unsigned short* wr = &WtS[(16 * kt + r16) * 136 + 8 * q];
            short8 w0 = *(const short8*)(const void*)(wr);
            short8 w1 = *(const short8*)(const void*)(wr + 32);
            short8 w2 = *(const short8*)(const void*)(wr + 64);
            short8 w3 = *(const short8*)(const void*)(wr + 96);
            f32x4 a = *(const f32x4*)&c0s[16 * kt + 4 * q];
            a = __builtin_amdgcn_mfma_f32_16x16x32_bf16(w0, fx2a.s8, a, 0, 0, 0);
            a = __builtin_amdgcn_mfma_f32_16x16x32_bf16(w1, fx2b.s8, a, 0, 0, 0);
            a = __builtin_amdgcn_mfma_f32_16x16x32_bf16(w2, fxa.s8,  a, 0, 0, 0);
            a = __builtin_amdgcn_mfma_f32_16x16x32_bf16(w3, fxb.s8,  a, 0, 0, 0);
            sc[kt][0] = a[0]; sc[kt][1] = a[1]; sc[kt][2] = a[2]; sc[kt][3] = a[3];
        }

        // ---- softmax over k: 16 in-lane values + lanes^16,^32 (same point p) ----
        float mx = sc[0][0];
        #pragma unroll
        for (int kt = 0; kt < 4; ++kt)
            #pragma unroll
            for (int rr = 0; rr < 4; ++rr) mx = fmaxf(mx, sc[kt][rr]);
        mx = fmaxf(mx, __shfl_xor(mx, 16));
        mx = fmaxf(mx, __shfl_xor(mx, 32));
        float z = 0.0f;
        #pragma unroll
        for (int kt = 0; kt < 4; ++kt)
            #pragma unroll
            for (int rr = 0; rr < 4; ++rr) {
                sc[kt][rr] = __expf(sc[kt][rr] - mx);
                z += sc[kt][rr];
            }
        z += __shfl_xor(z, 16);
        z += __shfl_xor(z, 32);
        float inv = 1.0f / z;
        const int p = 16 * w + r16;
        unsigned short* Qb = QtS[tile & 1];
        #pragma unroll
        for (int kt = 0; kt < 4; ++kt) {
            #pragma unroll
            for (int rr = 0; rr < 4; rr += 2) {
                float q0 = sc[kt][rr] * inv;
                float q1 = sc[kt][rr + 1] * inv;
                qsacc[kt][rr]     += q0;
                qsacc[kt][rr + 1] += q1;
                unsigned int pk = f2bf2(q0, q1);
                Qb[(16 * kt + 4 * q + rr)     * 72 + p] = (unsigned short)pk;
                Qb[(16 * kt + 4 * q + rr + 1) * 72 + p] = (unsigned short)(pk >> 16);
            }
        }

        // ---- phase-2 column loads for CURRENT tile (L1/L2-hot; in flight across barrier) ----
        float vle[16];
        {
            const float* xc = xt + dcol;
            #pragma unroll
            for (int c = 0; c < 2; ++c)
                #pragma unroll
                for (int j = 0; j < 8; ++j)
                    vle[8 * c + j] = xc[(32 * c + 8 * q + j) * D_];
        }

        // barrier WITHOUT vmcnt(0) drain (LDS visibility only) — keeps prefetches in flight
        asm volatile("s_waitcnt lgkmcnt(0)\n\ts_barrier" ::: "memory");

        // ================= phase 2: Qx[k][d], Qx2[k][d] =================
        U8 fxp0, fxp1, fx2p0, fx2p1;
        #pragma unroll
        for (int i = 0; i < 4; ++i) {
            float a0 = vle[2 * i], a1 = vle[2 * i + 1];
            float b0 = vle[8 + 2 * i], b1 = vle[8 + 2 * i + 1];
            fxp0.u[i]  = f2bf2(a0, a1);
            fxp1.u[i]  = f2bf2(b0, b1);
            fx2p0.u[i] = f2bf2(a0 * a0, a1 * a1);
            fx2p1.u[i] = f2bf2(b0 * b0, b1 * b1);
        }
        #pragma unroll
        for (int kt = 0; kt < 4; ++kt) {
            const unsigned short* qr = &Qb[(16 * kt + r16) * 72 + 8 * q];
            short8 aq0 = *(const short8*)(const void*)(qr);
            short8 aq1 = *(const short8*)(const void*)(qr + 32);
            accX[kt]  = __builtin_amdgcn_mfma_f32_16x16x32_bf16(aq0, fxp0.s8,  accX[kt],  0, 0, 0);
            accX2[kt] = __builtin_amdgcn_mfma_f32_16x16x32_bf16(aq0, fx2p0.s8, accX2[kt], 0, 0, 0);
            accX[kt]  = __builtin_amdgcn_mfma_f32_16x16x32_bf16(aq1, fxp1.s8,  accX[kt],  0, 0, 0);
            accX2[kt] = __builtin_amdgcn_mfma_f32_16x16x32_bf16(aq1, fx2p1.s8, accX2[kt], 0, 0, 0);
        }

        // rotate pipeline registers (renamed away by unroll)
        va = nva; vb = nvb; vc = nvc; vd = nvd;
    }

    // ---- write partials: f32 qsum[64] | bf16 qx[4096] | bf16 qx2[4096] ----
    char* rec = partials + ((size_t)bi * CHUNKS + chunk) * PART_STRIDE;
    float* part_qs = (float*)rec;
    unsigned short* part_qx  = (unsigned short*)(rec + 256);
    unsigned short* part_qx2 = part_qx + 4096;
    #pragma unroll
    for (int kt = 0; kt < 4; ++kt)
        #pragma unroll
        for (int rr = 0; rr < 4; ++rr) {
            int k = 16 * kt + 4 * q + rr;
            part_qx [k * 64 + 16 * w + r16] = f2bf(accX[kt][rr]);
            part_qx2[k * 64 + 16 * w + r16] = f2bf(accX2[kt][rr]);
        }
    #pragma unroll
    for (int kt = 0; kt < 4; ++kt)
        #pragma unroll
        for (int rr = 0; rr < 4; ++rr) {
            float v = qsacc[kt][rr];
            v += __shfl_xor(v, 1);
            v += __shfl_xor(v, 2);
            v += __shfl_xor(v, 4);
            v += __shfl_xor(v, 8);
            if (r16 == 0) qsum_s[w][16 * kt + 4 * q + rr] = v;
        }
    __syncthreads();
    if (t < 64)
        part_qs[t] = qsum_s[0][t] + qsum_s[1][t] + qsum_s[2][t] + qsum_s[3][t];
}

__global__ __launch_bounds__(256) void fv_finalize(const float* __restrict__ pi,
                                                   const float* __restrict__ mu,
                                                   const float* __restrict__ var,
                                                   const char* __restrict__ partials,
                                                   float* __restrict__ out) {
    int g = blockIdx.x * 256 + threadIdx.x;
    if (g >= B_ * OUT_PER_B) return;
    int b   = g / OUT_PER_B;
    int pos = g - b * OUT_PER_B;
    const char* base = partials + (size_t)b * CHUNKS * PART_STRIDE;
    const float invN = 1.0f / (float)N_;

    if (pos < 64) {
        float qs = 0.0f;
        for (int c = 0; c < CHUNKS; ++c)
            qs += ((const float*)(base + c * PART_STRIDE))[pos];
        out[g] = qs * invN - pi[pos];
    } else if (pos < 64 + 4096) {
        int idx = pos - 64;
        int k = idx >> 6;
        float qs = 0.0f, qx = 0.0f;
        for (int c = 0; c < CHUNKS; ++c) {
            const char* r = base + c * PART_STRIDE;
            qs += ((const float*)r)[k];
            qx += bf2f(((const unsigned short*)(r + 256))[idx]);
        }
        out[g] = (qx - qs * mu[idx]) * invN;
    } else {
        int idx = pos - 64 - 4096;
        int k = idx >> 6;
        float qs = 0.0f, qx = 0.0f, qx2 = 0.0f;
        for (int c = 0; c < CHUNKS; ++c) {
            const char* r = base + c * PART_STRIDE;
            qs  += ((const float*)r)[k];
            qx  += bf2f(((const unsigned short*)(r + 256))[idx]);
            qx2 += bf2f(((const unsigned short*)(r + 256))[4096 + idx]);
        }
        float m = mu[idx], v = var[idx];
        out[g] = (-qx2 - qs * m * m + qs * v + 2.0f * qx * m) * invN;
    }
}

extern "C" void kernel_launch(void* const* d_in, const int* in_sizes, int n_in,
                              void* d_out, int out_size, void* d_ws, size_t ws_size,
                              hipStream_t stream) {
    const float* x   = (const float*)d_in[0];
    const float* pi  = (const float*)d_in[1];
    const float* mu  = (const float*)d_in[2];
    const float* var = (const float*)d_in[3];
    float* ws = (float*)d_ws;
    char* partials = (char*)(ws + WS_PART_OFF);

    fv_prep<<<1, 256, 0, stream>>>(pi, mu, var, ws);
    fv_main<<<dim3(CHUNKS, B_), 256, 0, stream>>>(x, ws, partials);
    int total = B_ * OUT_PER_B;
    fv_finalize<<<(total + 255) / 256, 256, 0, stream>>>(pi, mu, var, partials,
                                                         (float*)d_out);
}

// Round 8
// 119.822 us; speedup vs baseline: 1.0723x; 1.0723x over previous
//
#include <hip/hip_runtime.h>
#include <hip/hip_bf16.h>
#include <math.h>

// Problem constants (fixed by the reference).
#define B_  16
#define N_  16384
#define D_  64
#define K_  64
#define OUT_PER_B (K_ + 2*K_*D_)   // 8256
#define CHUNKS 32
#define NTILES (N_ / CHUNKS / 64)  // 8

// ws layout: per (b,chunk) partial record at offset (b*CHUNKS+chunk)*PART_STRIDE:
//   f32 qsum[64] | bf16 qx[64*64] | bf16 qx2[64*64]   (16640 B)
#define PART_STRIDE (64*4 + 2*4096*2)   // 16640 bytes

typedef float f32x4 __attribute__((ext_vector_type(4)));
typedef short short8 __attribute__((ext_vector_type(8)));

union U8 { short8 s8; unsigned int u[4]; };

__device__ __forceinline__ unsigned short f2bf(float f) {
    union { float f; unsigned int u; } v; v.f = f;
    unsigned int r = v.u + 0x7FFFu + ((v.u >> 16) & 1u);   // round-to-nearest-even
    return (unsigned short)(r >> 16);
}

// packed RNE f32x2 -> bf16x2 (v_cvt_pk_bf16_f32 on gfx950)
__device__ __forceinline__ unsigned int f2bf2(float lo, float hi) {
    __hip_bfloat162 h = __float22bfloat162_rn(make_float2(lo, hi));
    unsigned int u;
    __builtin_memcpy(&u, &h, 4);
    return u;
}

__device__ __forceinline__ float bf2f(unsigned short u) {
    unsigned int v = ((unsigned int)u) << 16;
    float f;
    __builtin_memcpy(&f, &v, 4);
    return f;
}

// MFMA layouts (16x16x32 bf16, guide-verified):
//   A[m = lane&15][kk = (lane>>4)*8 + j]
//   B[kk = (lane>>4)*8 + j][n = lane&15]
//   C/D: col = lane&15, row = 4*(lane>>4) + reg
__global__ __launch_bounds__(256, 2) void fv_main(const float* __restrict__ x,
                                                  const float* __restrict__ pi,
                                                  const float* __restrict__ mu,
                                                  const float* __restrict__ var,
                                                  char* __restrict__ partials) {
    __shared__ __align__(16) unsigned short QtS[2][64 * 72];  // double-buffered Q^T[k][p]
    __shared__ float qsum_s[4][64];
    __shared__ float red[256];
    __shared__ float c0s[64];

    const int t    = threadIdx.x;
    const int w    = t >> 6;        // wave 0..3
    const int lane = t & 63;
    const int r16  = lane & 15;
    const int q    = lane >> 4;     // quad 0..3

    // ==== fused prep (R8): c0 cooperative, Wt fragments per-lane ====
    // c0 partial sums (exact replication of prep's summation order)
    {
        int k = t >> 2, pr = t & 3;
        float s = 0.0f;
        #pragma unroll
        for (int j = 0; j < 16; ++j) {
            int d = pr * 16 + j;
            float v = var[k * 64 + d];
            float m = mu[k * 64 + d];
            s += __logf(v) + m * m / v;
        }
        red[t] = s;
    }

    // Wt A-fragments straight from mu/var (same per-element ops as old fv_prep:
    // iv = 1.0f/v;  h0/h1 = -0.5f*iv;  h2/h3 = m*iv)
    short8 wfrag[4][4];
    #pragma unroll
    for (int kt = 0; kt < 4; ++kt) {
        const int k = 16 * kt + r16;
        const float* vr = var + k * 64 + 8 * q;
        const float* mr = mu  + k * 64 + 8 * q;
        float vv[16], mm[16];
        *(float4*)&vv[0]  = *(const float4*)(vr);
        *(float4*)&vv[4]  = *(const float4*)(vr + 4);
        *(float4*)&vv[8]  = *(const float4*)(vr + 32);
        *(float4*)&vv[12] = *(const float4*)(vr + 36);
        *(float4*)&mm[0]  = *(const float4*)(mr);
        *(float4*)&mm[4]  = *(const float4*)(mr + 4);
        *(float4*)&mm[8]  = *(const float4*)(mr + 32);
        *(float4*)&mm[12] = *(const float4*)(mr + 36);
        float iv[16];
        #pragma unroll
        for (int i = 0; i < 16; ++i) iv[i] = 1.0f / vv[i];
        U8 h0, h1, h2, h3;
        #pragma unroll
        for (int i = 0; i < 4; ++i) {
            h0.u[i] = f2bf2(-0.5f * iv[2*i],     -0.5f * iv[2*i + 1]);
            h1.u[i] = f2bf2(-0.5f * iv[8 + 2*i], -0.5f * iv[8 + 2*i + 1]);
            h2.u[i] = f2bf2(mm[2*i] * iv[2*i],   mm[2*i+1] * iv[2*i + 1]);
            h3.u[i] = f2bf2(mm[8+2*i] * iv[8+2*i], mm[8+2*i+1] * iv[8+2*i+1]);
        }
        wfrag[kt][0] = h0.s8; wfrag[kt][1] = h1.s8;
        wfrag[kt][2] = h2.s8; wfrag[kt][3] = h3.s8;
    }

    __syncthreads();            // red ready
    if ((t & 3) == 0) {
        int k = t >> 2;
        float sum = red[4 * k] + red[4 * k + 1] + red[4 * k + 2] + red[4 * k + 3];
        // D*log(2*pi) = 117.6241322501981
        c0s[k] = __logf(pi[k]) - 0.5f * (117.6241322502f + sum);
    }
    __syncthreads();            // c0s ready

    f32x4 c0v[4];
    #pragma unroll
    for (int kt = 0; kt < 4; ++kt)
        c0v[kt] = *(const f32x4*)&c0s[16 * kt + 4 * q];

    const int bi    = blockIdx.y;
    const int chunk = blockIdx.x;
    const int ppb   = N_ / CHUNKS;
    const float* xb = x + ((size_t)bi * N_ + (size_t)chunk * ppb) * D_;

    f32x4 accX[4]  = {};       // Qx  : k rows, d col = 16w + r16
    f32x4 accX2[4] = {};       // Qx2
    float qsacc[4][4] = {};    // per-lane Q sums (ks: 16kt + 4q + rr)

    const int rowoff = (16 * w + r16) * D_ + 8 * q;   // phase-1 row base
    const int dcol   = 16 * w + r16;                  // phase-2 column

    // ---- preload tile-0 phase-1 rows ----
    float4 va, vb, vc, vd;
    {
        const float* xr = xb + rowoff;
        va = *(const float4*)(xr);
        vb = *(const float4*)(xr + 4);
        vc = *(const float4*)(xr + 32);
        vd = *(const float4*)(xr + 36);
    }

    #pragma unroll 2
    for (int tile = 0; tile < NTILES; ++tile) {
        const float* xt = xb + (size_t)tile * 64 * D_;

        // ---- phase-2 column loads for CURRENT tile, issued at TOP of iteration (R8):
        //      lines already inbound from last iteration's row prefetch; ~500 cyc cover ----
        float vle[16];
        {
            const float* xc = xt + dcol;
            #pragma unroll
            for (int c = 0; c < 2; ++c)
                #pragma unroll
                for (int j = 0; j < 8; ++j)
                    vle[8 * c + j] = xc[(32 * c + 8 * q + j) * D_];
        }

        // ---- prefetch next tile's rows (stays in flight across the manual barrier) ----
        float4 nva, nvb, nvc, nvd;
        if (tile + 1 < NTILES) {
            const float* xr = xt + 64 * D_ + rowoff;
            nva = *(const float4*)(xr);
            nvb = *(const float4*)(xr + 4);
            nvc = *(const float4*)(xr + 32);
            nvd = *(const float4*)(xr + 36);
        }

        // ================= phase 1: S^T[k][p] =================
        U8 fxa, fxb, fx2a, fx2b;
        fxa.u[0]  = f2bf2(va.x, va.y);           fxa.u[1]  = f2bf2(va.z, va.w);
        fxa.u[2]  = f2bf2(vb.x, vb.y);           fxa.u[3]  = f2bf2(vb.z, vb.w);
        fxb.u[0]  = f2bf2(vc.x, vc.y);           fxb.u[1]  = f2bf2(vc.z, vc.w);
        fxb.u[2]  = f2bf2(vd.x, vd.y);           fxb.u[3]  = f2bf2(vd.z, vd.w);
        fx2a.u[0] = f2bf2(va.x*va.x, va.y*va.y); fx2a.u[1] = f2bf2(va.z*va.z, va.w*va.w);
        fx2a.u[2] = f2bf2(vb.x*vb.x, vb.y*vb.y); fx2a.u[3] = f2bf2(vb.z*vb.z, vb.w*vb.w);
        fx2b.u[0] = f2bf2(vc.x*vc.x, vc.y*vc.y); fx2b.u[1] = f2bf2(vc.z*vc.z, vc.w*vc.w);
        fx2b.u[2] = f2bf2(vd.x*vd.x, vd.y*vd.y); fx2b.u[3] = f2bf2(vd.z*vd.z, vd.w*vd.w);

        float sc[4][4];
        #pragma unroll
        for (int kt = 0; kt < 4; ++kt) {
            f32x4 a = c0v[kt];
            a = __builtin_amdgcn_mfma_f32_16x16x32_bf16(wfrag[kt][0], fx2a.s8, a, 0, 0, 0);
            a = __builtin_amdgcn_mfma_f32_16x16x32_bf16(wfrag[kt][1], fx2b.s8, a, 0, 0, 0);
            a = __builtin_amdgcn_mfma_f32_16x16x32_bf16(wfrag[kt][2], fxa.s8,  a, 0, 0, 0);
            a = __builtin_amdgcn_mfma_f32_16x16x32_bf16(wfrag[kt][3], fxb.s8,  a, 0, 0, 0);
            sc[kt][0] = a[0]; sc[kt][1] = a[1]; sc[kt][2] = a[2]; sc[kt][3] = a[3];
        }

        // ---- softmax over k: 16 in-lane values + lanes^16,^32 (same point p) ----
        float mx = sc[0][0];
        #pragma unroll
        for (int kt = 0; kt < 4; ++kt)
            #pragma unroll
            for (int rr = 0; rr < 4; ++rr) mx = fmaxf(mx, sc[kt][rr]);
        mx = fmaxf(mx, __shfl_xor(mx, 16));
        mx = fmaxf(mx, __shfl_xor(mx, 32));
        float z = 0.0f;
        #pragma unroll
        for (int kt = 0; kt < 4; ++kt)
            #pragma unroll
            for (int rr = 0; rr < 4; ++rr) {
                sc[kt][rr] = __expf(sc[kt][rr] - mx);
                z += sc[kt][rr];
            }
        z += __shfl_xor(z, 16);
        z += __shfl_xor(z, 32);
        float inv = 1.0f / z;
        const int p = 16 * w + r16;
        unsigned short* Qb = QtS[tile & 1];
        #pragma unroll
        for (int kt = 0; kt < 4; ++kt) {
            #pragma unroll
            for (int rr = 0; rr < 4; rr += 2) {
                float q0 = sc[kt][rr] * inv;
                float q1 = sc[kt][rr + 1] * inv;
                qsacc[kt][rr]     += q0;
                qsacc[kt][rr + 1] += q1;
                unsigned int pk = f2bf2(q0, q1);
                Qb[(16 * kt + 4 * q + rr)     * 72 + p] = (unsigned short)pk;
                Qb[(16 * kt + 4 * q + rr + 1) * 72 + p] = (unsigned short)(pk >> 16);
            }
        }

        // barrier WITHOUT vmcnt(0) drain (LDS visibility only) — keeps prefetches in flight
        asm volatile("s_waitcnt lgkmcnt(0)\n\ts_barrier" ::: "memory");

        // ================= phase 2: Qx[k][d], Qx2[k][d] =================
        U8 fxp0, fxp1, fx2p0, fx2p1;
        #pragma unroll
        for (int i = 0; i < 4; ++i) {
            float a0 = vle[2 * i], a1 = vle[2 * i + 1];
            float b0 = vle[8 + 2 * i], b1 = vle[8 + 2 * i + 1];
            fxp0.u[i]  = f2bf2(a0, a1);
            fxp1.u[i]  = f2bf2(b0, b1);
            fx2p0.u[i] = f2bf2(a0 * a0, a1 * a1);
            fx2p1.u[i] = f2bf2(b0 * b0, b1 * b1);
        }
        #pragma unroll
        for (int kt = 0; kt < 4; ++kt) {
            const unsigned short* qr = &Qb[(16 * kt + r16) * 72 + 8 * q];
            short8 aq0 = *(const short8*)(const void*)(qr);
            short8 aq1 = *(const short8*)(const void*)(qr + 32);
            accX[kt]  = __builtin_amdgcn_mfma_f32_16x16x32_bf16(aq0, fxp0.s8,  accX[kt],  0, 0, 0);
            accX2[kt] = __builtin_amdgcn_mfma_f32_16x16x32_bf16(aq0, fx2p0.s8, accX2[kt], 0, 0, 0);
            accX[kt]  = __builtin_amdgcn_mfma_f32_16x16x32_bf16(aq1, fxp1.s8,  accX[kt],  0, 0, 0);
            accX2[kt] = __builtin_amdgcn_mfma_f32_16x16x32_bf16(aq1, fx2p1.s8, accX2[kt], 0, 0, 0);
        }

        // rotate pipeline registers (renamed away by unroll)
        va = nva; vb = nvb; vc = nvc; vd = nvd;
    }

    // ---- write partials: f32 qsum[64] | bf16 qx[4096] | bf16 qx2[4096] ----
    char* rec = partials + ((size_t)bi * CHUNKS + chunk) * PART_STRIDE;
    float* part_qs = (float*)rec;
    unsigned short* part_qx  = (unsigned short*)(rec + 256);
    unsigned short* part_qx2 = part_qx + 4096;
    #pragma unroll
    for (int kt = 0; kt < 4; ++kt)
        #pragma unroll
        for (int rr = 0; rr < 4; ++rr) {
            int k = 16 * kt + 4 * q + rr;
            part_qx [k * 64 + 16 * w + r16] = f2bf(accX[kt][rr]);
            part_qx2[k * 64 + 16 * w + r16] = f2bf(accX2[kt][rr]);
        }
    #pragma unroll
    for (int kt = 0; kt < 4; ++kt)
        #pragma unroll
        for (int rr = 0; rr < 4; ++rr) {
            float v = qsacc[kt][rr];
            v += __shfl_xor(v, 1);
            v += __shfl_xor(v, 2);
            v += __shfl_xor(v, 4);
            v += __shfl_xor(v, 8);
            if (r16 == 0) qsum_s[w][16 * kt + 4 * q + rr] = v;
        }
    __syncthreads();
    if (t < 64)
        part_qs[t] = qsum_s[0][t] + qsum_s[1][t] + qsum_s[2][t] + qsum_s[3][t];
}

__global__ __launch_bounds__(256) void fv_finalize(const float* __restrict__ pi,
                                                   const float* __restrict__ mu,
                                                   const float* __restrict__ var,
                                                   const char* __restrict__ partials,
                                                   float* __restrict__ out) {
    int g = blockIdx.x * 256 + threadIdx.x;
    if (g >= B_ * OUT_PER_B) return;
    int b   = g / OUT_PER_B;
    int pos = g - b * OUT_PER_B;
    const char* base = partials + (size_t)b * CHUNKS * PART_STRIDE;
    const float invN = 1.0f / (float)N_;

    if (pos < 64) {
        float qs = 0.0f;
        for (int c = 0; c < CHUNKS; ++c)
            qs += ((const float*)(base + c * PART_STRIDE))[pos];
        out[g] = qs * invN - pi[pos];
    } else if (pos < 64 + 4096) {
        int idx = pos - 64;
        int k = idx >> 6;
        float qs = 0.0f, qx = 0.0f;
        for (int c = 0; c < CHUNKS; ++c) {
            const char* r = base + c * PART_STRIDE;
            qs += ((const float*)r)[k];
            qx += bf2f(((const unsigned short*)(r + 256))[idx]);
        }
        out[g] = (qx - qs * mu[idx]) * invN;
    } else {
        int idx = pos - 64 - 4096;
        int k = idx >> 6;
        float qs = 0.0f, qx = 0.0f, qx2 = 0.0f;
        for (int c = 0; c < CHUNKS; ++c) {
            const char* r = base + c * PART_STRIDE;
            qs  += ((const float*)r)[k];
            qx  += bf2f(((const unsigned short*)(r + 256))[idx]);
            qx2 += bf2f(((const unsigned short*)(r + 256))[4096 + idx]);
        }
        float m = mu[idx], v = var[idx];
        out[g] = (-qx2 - qs * m * m + qs * v + 2.0f * qx * m) * invN;
    }
}

extern "C" void kernel_launch(void* const* d_in, const int* in_sizes, int n_in,
                              void* d_out, int out_size, void* d_ws, size_t ws_size,
                              hipStream_t stream) {
    const float* x   = (const float*)d_in[0];
    const float* pi  = (const float*)d_in[1];
    const float* mu  = (const float*)d_in[2];
    const float* var = (const float*)d_in[3];
    char* partials = (char*)d_ws;

    fv_main<<<dim3(CHUNKS, B_), 256, 0, stream>>>(x, pi, mu, var, partials);
    int total = B_ * OUT_PER_B;
    fv_finalize<<<(total + 255) / 256, 256, 0, stream>>>(pi, mu, var, partials,
                                                         (float*)d_out);
}